// Round 9
// baseline (90.868 us; speedup 1.0000x reference)
//
#include <hip/hip_runtime.h>
#include <math.h>

#define B_ 16
#define T_ 12
#define N_ 325
#define C_ 64
#define K_ 8
#define L_ 3900            // N_*T_
#define M_ 249600          // C_*L_
#define LCH_ 61            // ceil(L_/64)
#define LOG2PI_ 1.8378770664093453f

// ---------------- workspace layout (floats) ----------------
#define OFF_LOGGAM 0            // 128
#define OFF_PART   128          // 256 (16 used)
#define OFF_CTR    384          // 17 unsigned: ctrb[16] + ctr2
#define OFF_MUS    512          // 8192
#define OFF_ISIG   8704         // 8192
#define OFF_T1     16896        // 8192
#define OFF_SPART  25088        // 7808 = 128*61
#define OFF_GPART  32896        // 7808 = 976*8
#define OFF_P      40704        // 499200 = B*K*L
#define OFF_CONVP  539904       // 998400 = 61*16384
// total = 1538304 floats = 6.15 MB

// K1: block = (lc, b-pair). lc = bid&63 (same-lc blocks 64 apart -> same XCD,
//     so each 128KB Wg slice lives in ONE L2). Stages 2 rep_aug tiles,
//     L2-normalizes in-LDS; each Wg load feeds 4 FMAs (2 b x 2 k).
__global__ __launch_bounds__(256) void k1(const float* __restrict__ rep_aug,
                                          const float* __restrict__ Wg,
                                          const float* __restrict__ Wmu,
                                          const float* __restrict__ Wsg,
                                          float* __restrict__ gpart,
                                          float* __restrict__ convp) {
    int lc = blockIdx.x & 63, bp = blockIdx.x >> 6;
    if (lc >= LCH_) return;
    int b0 = bp * 2, b1 = b0 + 1;
    int l0 = lc * 64;
    __shared__ float ldsA0[64 * 65];     // [ll][c]
    __shared__ float ldsA1[64 * 65];
    __shared__ float sc0[64], sc1[64];
    __shared__ float ldsW[16 * 64];
    int tid = threadIdx.x, lane = tid & 63, wv = tid >> 6;
    const float4* r4 = (const float4*)rep_aug;
    for (int i4 = tid; i4 < 2048; i4 += 256) {
        int bsel = i4 >> 10, ll = (i4 >> 4) & 63, c4 = i4 & 15;
        int l = l0 + ll;
        int b = bsel ? b1 : b0;
        float4 v = make_float4(0.f, 0.f, 0.f, 0.f);
        if (l < L_) {
            int n = l / T_, t = l - n * T_;
            v = r4[(size_t)((b * T_ + t) * N_ + n) * 16 + c4];
        }
        float* dst = (bsel ? ldsA1 : ldsA0) + ll * 65 + c4 * 4;
        dst[0] = v.x; dst[1] = v.y; dst[2] = v.z; dst[3] = v.w;
    }
    for (int idx = tid; idx < 1024; idx += 256) {
        int r = idx >> 6, ll = idx & 63;
        int l = l0 + ll;
        float w = 0.0f;
        if (l < L_) w = (r < 8) ? Wmu[r * L_ + l] : Wsg[(r - 8) * L_ + l];
        ldsW[r * 64 + ll] = w;
    }
    __syncthreads();
    // sumsq: 128 rows (2 tiles x 64), 32 per wave
    #pragma unroll 4
    for (int i = 0; i < 32; ++i) {
        int p = wv * 32 + i;                 // 0..127
        float x = (p < 64 ? ldsA0[p * 65 + lane] : ldsA1[(p - 64) * 65 + lane]);
        float ss = x * x;
        #pragma unroll
        for (int m = 1; m < 64; m <<= 1) ss += __shfl_xor(ss, m);
        if (lane == 0) {
            float s = 1.0f / fmaxf(sqrtf(ss), 1e-12f);
            if (p < 64) sc0[p] = s; else sc1[p - 64] = s;
        }
    }
    __syncthreads();

    // ---- gamma partials: lane = l (coalesced Wg), wave wv owns k0,k1 ----
    int k0 = wv * 2, k1i = k0 + 1;
    int lg = l0 + lane;
    int lcl = lg < L_ ? lg : 0;              // invalid lanes have a==0
    const float* pg0 = Wg + (size_t)k0 * M_ + lcl;
    const float* pg1 = Wg + (size_t)k1i * M_ + lcl;
    float s0v = sc0[lane], s1v = sc1[lane];
    float g00 = 0.f, g01 = 0.f, g10 = 0.f, g11 = 0.f;
    #pragma unroll 8
    for (int c = 0; c < 64; ++c) {
        float w0 = pg0[(size_t)c * L_];
        float w1 = pg1[(size_t)c * L_];
        float a0 = ldsA0[lane * 65 + c] * s0v;
        float a1 = ldsA1[lane * 65 + c] * s1v;
        g00 = fmaf(a0, w0, g00);
        g01 = fmaf(a0, w1, g01);
        g10 = fmaf(a1, w0, g10);
        g11 = fmaf(a1, w1, g11);
    }
    #pragma unroll
    for (int m = 1; m < 64; m <<= 1) {
        g00 += __shfl_xor(g00, m); g01 += __shfl_xor(g01, m);
        g10 += __shfl_xor(g10, m); g11 += __shfl_xor(g11, m);
    }
    if (lane == 0) {
        gpart[(size_t)(lc * 16 + b0) * 8 + k0]  = g00;
        gpart[(size_t)(lc * 16 + b0) * 8 + k1i] = g01;
        gpart[(size_t)(lc * 16 + b1) * 8 + k0]  = g10;
        gpart[(size_t)(lc * 16 + b1) * 8 + k1i] = g11;
    }

    // ---- conv partials: c = lane, kk = wv (LDS-only), both b's ----
    int c = lane, kk = wv;
    const float* w0p = &ldsW[(kk * 4 + 0) * 64];
    const float* w1p = &ldsW[(kk * 4 + 1) * 64];
    const float* w2p = &ldsW[(kk * 4 + 2) * 64];
    const float* w3p = &ldsW[(kk * 4 + 3) * 64];
    float a00 = 0.f, a01 = 0.f, a02 = 0.f, a03 = 0.f;
    float a10 = 0.f, a11 = 0.f, a12 = 0.f, a13 = 0.f;
    #pragma unroll 8
    for (int l = 0; l < 64; ++l) {
        float av0 = ldsA0[l * 65 + c] * sc0[l];
        float av1 = ldsA1[l * 65 + c] * sc1[l];
        float w0 = w0p[l], w1 = w1p[l], w2 = w2p[l], w3 = w3p[l];
        a00 = fmaf(av0, w0, a00); a01 = fmaf(av0, w1, a01);
        a02 = fmaf(av0, w2, a02); a03 = fmaf(av0, w3, a03);
        a10 = fmaf(av1, w0, a10); a11 = fmaf(av1, w1, a11);
        a12 = fmaf(av1, w2, a12); a13 = fmaf(av1, w3, a13);
    }
    float* d0 = convp + (size_t)lc * 16384 + b0 * 1024 + c * 16 + kk * 4;
    d0[0] = a00; d0[1] = a01; d0[2] = a02; d0[3] = a03;
    float* d1 = convp + (size_t)lc * 16384 + b1 * 1024 + c * 16 + kk * 4;
    d1[0] = a10; d1[1] = a11; d1[2] = a12; d1[3] = a13;
}

// K2: convfin (blocks 0..63) + gamma reduce+log-softmax (64..79) + ctr resets
__global__ __launch_bounds__(256) void k2(const float* __restrict__ convp,
                                          const float* __restrict__ gpart,
                                          const float* __restrict__ bmu,
                                          const float* __restrict__ bsg,
                                          float* __restrict__ mus,
                                          float* __restrict__ isig,
                                          float* __restrict__ t1,
                                          float* __restrict__ loggam,
                                          unsigned* __restrict__ ctr) {
    int tid = threadIdx.x;
    if (blockIdx.x < 64) {
        int o = blockIdx.x * 256 + tid;     // 0..16383 = b*1024 + c*16 + kk
        float s = 0.0f;
        #pragma unroll 8
        for (int lc = 0; lc < LCH_; ++lc) s += convp[(size_t)lc * 16384 + o];
        int bc = o >> 4, kk = o & 15, k = kk & 7;
        if (kk < 8) {
            mus[bc * 8 + k] = s + bmu[k];
        } else {
            float logit = s + bsg[k];
            isig[bc * 8 + k] = expf(-logit);
            t1[bc * 8 + k] = -logit - 0.5f * LOG2PI_;
        }
    } else {
        int b = blockIdx.x - 64;
        if (b == 0 && tid < 17) ctr[tid] = 0u;   // reset ctrb[16] + ctr2
        if (tid < 64) {
            int lc = tid;
            bool valid = lc < LCH_;
            float g[K_];
            #pragma unroll
            for (int k = 0; k < K_; ++k)
                g[k] = valid ? gpart[(size_t)(lc * 16 + b) * 8 + k] : 0.0f;
            #pragma unroll
            for (int k = 0; k < K_; ++k)
                #pragma unroll
                for (int m = 1; m < 64; m <<= 1) g[k] += __shfl_xor(g[k], m);
            if (tid == 0) {
                float mx = -1e30f;
                #pragma unroll
                for (int k = 0; k < K_; ++k) mx = fmaxf(mx, g[k]);
                float sum = 0.0f;
                #pragma unroll
                for (int k = 0; k < K_; ++k) sum += expf(g[k] - mx);
                float lse = mx + logf(sum);
                #pragma unroll
                for (int k = 0; k < K_; ++k) loggam[b * 8 + k] = g[k] - lse;
            }
        }
    }
}

// K3: prod + per-b finisher + global finisher. Block = lc*16+b, so all 61
//     blocks of batch b share one XCD (bid%8 = b%8): P/Spart reads are
//     L2-local for the finisher. Release/acquire agent atomics only —
//     NO __threadfence (R7: device fences on the every-block path ~+100µs).
__global__ __launch_bounds__(256) void k3(const float* __restrict__ rep,
                                          const float* __restrict__ mus,
                                          const float* __restrict__ isig,
                                          const float* __restrict__ t1,
                                          const float* __restrict__ loggam,
                                          float* __restrict__ P,
                                          float* __restrict__ Spart,
                                          float* __restrict__ part,
                                          unsigned* __restrict__ ctr,
                                          float* __restrict__ out) {
    int b = blockIdx.x & 15, lc = blockIdx.x >> 4;
    int l0 = lc * 64;
    __shared__ float ldsA[64 * 65];
    __shared__ float sc[64];
    __shared__ float ldsMu[512], ldsIs[512], ldsT1[512];
    int tid = threadIdx.x, lane = tid & 63, wv = tid >> 6;
    const float4* r4 = (const float4*)rep;
    for (int i4 = tid; i4 < 1024; i4 += 256) {
        int ll = i4 >> 4, c4 = i4 & 15;
        int l = l0 + ll;
        float4 v = make_float4(0.f, 0.f, 0.f, 0.f);
        if (l < L_) {
            int n = l / T_, t = l - n * T_;
            v = r4[(size_t)((b * T_ + t) * N_ + n) * 16 + c4];
        }
        int base = ll * 65 + c4 * 4;
        ldsA[base] = v.x; ldsA[base+1] = v.y; ldsA[base+2] = v.z; ldsA[base+3] = v.w;
    }
    for (int idx = tid; idx < 512; idx += 256) {
        ldsMu[idx] = mus[b * 512 + idx];
        ldsIs[idx] = isig[b * 512 + idx];
        ldsT1[idx] = t1[b * 512 + idx];
    }
    __syncthreads();
    #pragma unroll 4
    for (int i = 0; i < 16; ++i) {
        int p = wv * 16 + i;
        float x = ldsA[p * 65 + lane];
        float ss = x * x;
        #pragma unroll
        for (int m = 1; m < 64; m <<= 1) ss += __shfl_xor(ss, m);
        if (lane == 0) sc[p] = 1.0f / fmaxf(sqrtf(ss), 1e-12f);
    }
    __syncthreads();
    int l = l0 + lane;
    bool valid = l < L_;
    int k0 = wv * 2, k1i = k0 + 1;
    float scv = sc[lane];
    float p0 = 1.0f, p1 = 1.0f;
    #pragma unroll 8
    for (int c = 0; c < 64; ++c) {
        float a = ldsA[lane * 65 + c] * scv;
        float z0 = (a - ldsMu[c * 8 + k0]) * ldsIs[c * 8 + k0];
        p0 *= ldsT1[c * 8 + k0] - 0.5f * z0 * z0;
        float z1 = (a - ldsMu[c * 8 + k1i]) * ldsIs[c * 8 + k1i];
        p1 *= ldsT1[c * 8 + k1i] - 0.5f * z1 * z1;
    }
    if (!valid) { p0 = 0.0f; p1 = 0.0f; }
    if (valid) {
        P[(size_t)(b * K_ + k0) * L_ + l] = p0;
        P[(size_t)(b * K_ + k1i) * L_ + l] = p1;
    }
    float v0 = p0 * p0, v1 = p1 * p1;
    #pragma unroll
    for (int m = 1; m < 64; m <<= 1) { v0 += __shfl_xor(v0, m); v1 += __shfl_xor(v1, m); }
    if (lane == 0) {
        Spart[(size_t)(b * K_ + k0) * LCH_ + lc] = v0;
        Spart[(size_t)(b * K_ + k1i) * LCH_ + lc] = v1;
    }

    // ---- per-b completion: last of the 61 blocks of b does the whole-b LSE ----
    __syncthreads();
    __shared__ bool lastB;
    if (tid == 0) {
        unsigned old = __hip_atomic_fetch_add(&ctr[b], 1u, __ATOMIC_ACQ_REL,
                                              __HIP_MEMORY_SCOPE_AGENT);
        lastB = (old == (unsigned)(LCH_ - 1));
    }
    __syncthreads();
    if (!lastB) return;

    __shared__ float invk[8], lgk[8];
    if (tid < 8) {
        float s = 0.0f;
        #pragma unroll 8
        for (int i = 0; i < LCH_; ++i) s += Spart[(size_t)(b * 8 + tid) * LCH_ + i];
        invk[tid] = 1.0f / fmaxf(sqrtf(s), 1e-12f);
        lgk[tid] = loggam[b * 8 + tid];
    }
    __syncthreads();
    float ll = 0.0f;
    for (int i = 0; i < 16; ++i) {
        int l2 = tid + 256 * i;
        if (l2 < L_) {
            float v[K_];
            float mx = -1e30f;
            #pragma unroll
            for (int k = 0; k < K_; ++k) {
                v[k] = P[(size_t)(b * K_ + k) * L_ + l2] * invk[k] + lgk[k];
                mx = fmaxf(mx, v[k]);
            }
            float s = 0.0f;
            #pragma unroll
            for (int k = 0; k < K_; ++k) s += expf(v[k] - mx);
            ll += mx + logf(s);
        }
    }
    #pragma unroll
    for (int m = 1; m < 64; m <<= 1) ll += __shfl_xor(ll, m);
    __shared__ float red[4];
    __shared__ bool last2;
    if (lane == 0) red[wv] = ll;
    __syncthreads();
    if (tid == 0) {
        float v = red[0] + red[1] + red[2] + red[3];
        __hip_atomic_store(&part[b], v, __ATOMIC_RELEASE, __HIP_MEMORY_SCOPE_AGENT);
        unsigned old = __hip_atomic_fetch_add(&ctr[16], 1u, __ATOMIC_ACQ_REL,
                                              __HIP_MEMORY_SCOPE_AGENT);
        last2 = (old == 15u);
    }
    __syncthreads();
    if (last2 && tid == 0) {
        double s = 0.0;
        #pragma unroll
        for (int b2 = 0; b2 < B_; ++b2)
            s += (double)__hip_atomic_load(&part[b2], __ATOMIC_ACQUIRE,
                                           __HIP_MEMORY_SCOPE_AGENT);
        out[0] = (float)(-s / ((double)B_ * (double)L_));
    }
}

extern "C" void kernel_launch(void* const* d_in, const int* in_sizes, int n_in,
                              void* d_out, int out_size, void* d_ws, size_t ws_size,
                              hipStream_t stream) {
    const float* rep     = (const float*)d_in[0];
    const float* rep_aug = (const float*)d_in[1];
    const float* Wg      = (const float*)d_in[2];
    const float* Wmu     = (const float*)d_in[3];
    const float* bmu     = (const float*)d_in[4];
    const float* Wsg     = (const float*)d_in[5];
    const float* bsg     = (const float*)d_in[6];
    float* out = (float*)d_out;
    float* ws  = (float*)d_ws;

    float* loggam  = ws + OFF_LOGGAM;
    float* part    = ws + OFF_PART;
    unsigned* ctr  = (unsigned*)(ws + OFF_CTR);
    float* mus     = ws + OFF_MUS;
    float* isig    = ws + OFF_ISIG;
    float* t1      = ws + OFF_T1;
    float* Spart   = ws + OFF_SPART;
    float* gpart   = ws + OFF_GPART;
    float* P       = ws + OFF_P;
    float* convp   = ws + OFF_CONVP;

    k1<<<512, 256, 0, stream>>>(rep_aug, Wg, Wmu, Wsg, gpart, convp);
    k2<<<80, 256, 0, stream>>>(convp, gpart, bmu, bsg, mus, isig, t1, loggam, ctr);
    k3<<<B_ * LCH_, 256, 0, stream>>>(rep, mus, isig, t1, loggam, P, Spart, part, ctr, out);
}

// Round 10
// 79.755 us; speedup vs baseline: 1.1393x; 1.1393x over previous
//
#include <hip/hip_runtime.h>
#include <math.h>

#define B_ 16
#define T_ 12
#define N_ 325
#define C_ 64
#define K_ 8
#define L_ 3900            // N_*T_
#define M_ 249600          // C_*L_
#define M4_ 62400          // M_/4
#define LCH_ 61            // ceil(L_/64)
#define LOG2PI_ 1.8378770664093453f

// ---------------- workspace layout (floats) ----------------
#define OFF_PART   0            // 16
#define OFF_CTR    64           // 1 unsigned
#define OFF_MUS    128          // 8192
#define OFF_ISIG   8320         // 8192
#define OFF_T1     16512        // 8192
#define OFF_SPART  24704        // 7808 = 128*61
#define OFF_GPARTT 32512        // 124800 = 128*975 (transposed)
#define OFF_P      157312       // 499200 = B*K*L
#define OFF_AAUG   656512       // 3993600 = B*C*L
#define OFF_CONVP  4650112      // 998400 = 61*16384
// total = 5648512 floats = 22.6 MB

// kA: per (b, l-chunk 64): stage raw rep_aug tile, L2-normalize over C in-LDS,
//     write normalized transposed Aaug chunk AND conv partials. (R5-verified)
__global__ __launch_bounds__(256) void kA(const float* __restrict__ rep_aug,
                                          const float* __restrict__ Wmu,
                                          const float* __restrict__ Wsg,
                                          float* __restrict__ Aaug,
                                          float* __restrict__ convp) {
    int b = blockIdx.x / LCH_, lc = blockIdx.x - b * LCH_;
    int l0 = lc * 64;
    __shared__ float ldsA[64 * 65];      // [ll][c]
    __shared__ float sc[64];
    __shared__ float ldsW[16 * 64];
    int tid = threadIdx.x, lane = tid & 63, wv = tid >> 6;
    const float4* r4 = (const float4*)rep_aug;
    for (int i4 = tid; i4 < 1024; i4 += 256) {
        int ll = i4 >> 4, c4 = i4 & 15;
        int l = l0 + ll;
        float4 v = make_float4(0.f, 0.f, 0.f, 0.f);
        if (l < L_) {
            int n = l / T_, t = l - n * T_;
            v = r4[(size_t)((b * T_ + t) * N_ + n) * 16 + c4];
        }
        int base = ll * 65 + c4 * 4;
        ldsA[base] = v.x; ldsA[base+1] = v.y; ldsA[base+2] = v.z; ldsA[base+3] = v.w;
    }
    for (int idx = tid; idx < 1024; idx += 256) {
        int r = idx >> 6, ll = idx & 63;
        int l = l0 + ll;
        float w = 0.0f;
        if (l < L_) w = (r < 8) ? Wmu[r * L_ + l] : Wsg[(r - 8) * L_ + l];
        ldsW[r * 64 + ll] = w;
    }
    __syncthreads();
    #pragma unroll 4
    for (int i = 0; i < 16; ++i) {
        int p = wv * 16 + i;
        float x = ldsA[p * 65 + lane];
        float ss = x * x;
        #pragma unroll
        for (int m = 1; m < 64; m <<= 1) ss += __shfl_xor(ss, m);
        if (lane == 0) sc[p] = 1.0f / fmaxf(sqrtf(ss), 1e-12f);
    }
    __syncthreads();
    // write normalized transposed chunk: 64 consecutive floats per c row
    for (int idx = tid; idx < 4096; idx += 256) {
        int c = idx >> 6, ll = idx & 63;
        int l = l0 + ll;
        if (l < L_)
            Aaug[(size_t)(b * C_ + c) * L_ + l] = ldsA[ll * 65 + c] * sc[ll];
    }
    // conv partials: thread owns (c, 4 k's)
    int c = lane, kk = wv;
    const float* w0 = &ldsW[(kk * 4 + 0) * 64];
    const float* w1 = &ldsW[(kk * 4 + 1) * 64];
    const float* w2 = &ldsW[(kk * 4 + 2) * 64];
    const float* w3 = &ldsW[(kk * 4 + 3) * 64];
    float a0 = 0.f, a1 = 0.f, a2 = 0.f, a3 = 0.f;
    #pragma unroll 8
    for (int l = 0; l < 64; ++l) {
        float a = ldsA[l * 65 + c] * sc[l];
        a0 = fmaf(a, w0[l], a0);
        a1 = fmaf(a, w1[l], a1);
        a2 = fmaf(a, w2[l], a2);
        a3 = fmaf(a, w3[l], a3);
    }
    float* dst = convp + (size_t)lc * 16384 + b * 1024 + c * 16 + kk * 4;
    dst[0] = a0; dst[1] = a1; dst[2] = a2; dst[3] = a3;
}

// kB: gamma logit partials (blocks 0..974, Wg read ONCE, coalesced float4)
//     + convfin (blocks 975..1038) + ctr reset. (R5-verified bodies)
__global__ __launch_bounds__(256) void kB(const float* __restrict__ Aaug,
                                          const float* __restrict__ Wg,
                                          const float* __restrict__ convp,
                                          const float* __restrict__ bmu,
                                          const float* __restrict__ bsg,
                                          float* __restrict__ gpartT,
                                          float* __restrict__ mus,
                                          float* __restrict__ isig,
                                          float* __restrict__ t1,
                                          unsigned* __restrict__ ctr) {
    int tid = threadIdx.x, lane = tid & 63, wv = tid >> 6;
    if (blockIdx.x < 975) {
        const float4* A4 = (const float4*)Aaug;
        const float4* W4 = (const float4*)Wg;
        int m4 = blockIdx.x * 64 + lane;
        float4 w[K_];
        #pragma unroll
        for (int k = 0; k < K_; ++k) w[k] = W4[(size_t)k * M4_ + m4];
        float acc[4][K_];
        #pragma unroll
        for (int bb = 0; bb < 4; ++bb) {
            float4 a = A4[(size_t)(wv * 4 + bb) * M4_ + m4];
            #pragma unroll
            for (int k = 0; k < K_; ++k)
                acc[bb][k] = a.x * w[k].x + a.y * w[k].y + a.z * w[k].z + a.w * w[k].w;
        }
        __shared__ float red[128];
        #pragma unroll
        for (int bb = 0; bb < 4; ++bb)
            #pragma unroll
            for (int k = 0; k < K_; ++k) {
                float v = acc[bb][k];
                #pragma unroll
                for (int m = 1; m < 64; m <<= 1) v += __shfl_xor(v, m);
                if (lane == 0) red[wv * 32 + bb * 8 + k] = v;
            }
        __syncthreads();
        // red index = b*8+k; write transposed for kD's coalesced reduce
        if (tid < 128) gpartT[(size_t)tid * 975 + blockIdx.x] = red[tid];
    } else {
        if (blockIdx.x == 975 && tid == 0) *ctr = 0u;   // reset kD's counter
        int o = (blockIdx.x - 975) * 256 + tid;     // 0..16383 = b*1024+c*16+kk
        float s = 0.0f;
        #pragma unroll 8
        for (int lc = 0; lc < LCH_; ++lc) s += convp[(size_t)lc * 16384 + o];
        int bc = o >> 4, kk = o & 15, k = kk & 7;
        if (kk < 8) {
            mus[bc * 8 + k] = s + bmu[k];
        } else {
            float logit = s + bsg[k];
            isig[bc * 8 + k] = expf(-logit);
            t1[bc * 8 + k] = -logit - 0.5f * LOG2PI_;
        }
    }
}

// kC: prod only (R5-verified body). Block = (b, lc): P and Spart from raw rep.
__global__ __launch_bounds__(256) void kC(const float* __restrict__ rep,
                                          const float* __restrict__ mus,
                                          const float* __restrict__ isig,
                                          const float* __restrict__ t1,
                                          float* __restrict__ P,
                                          float* __restrict__ Spart) {
    int b = blockIdx.x & 15, lc = blockIdx.x >> 4;   // bid%8 = b%8 -> XCD pin
    int l0 = lc * 64;
    __shared__ float ldsA[64 * 65];
    __shared__ float sc[64];
    __shared__ float ldsMu[512], ldsIs[512], ldsT1[512];
    int tid = threadIdx.x, lane = tid & 63, wv = tid >> 6;
    const float4* r4 = (const float4*)rep;
    for (int i4 = tid; i4 < 1024; i4 += 256) {
        int ll = i4 >> 4, c4 = i4 & 15;
        int l = l0 + ll;
        float4 v = make_float4(0.f, 0.f, 0.f, 0.f);
        if (l < L_) {
            int n = l / T_, t = l - n * T_;
            v = r4[(size_t)((b * T_ + t) * N_ + n) * 16 + c4];
        }
        int base = ll * 65 + c4 * 4;
        ldsA[base] = v.x; ldsA[base+1] = v.y; ldsA[base+2] = v.z; ldsA[base+3] = v.w;
    }
    for (int idx = tid; idx < 512; idx += 256) {
        ldsMu[idx] = mus[b * 512 + idx];
        ldsIs[idx] = isig[b * 512 + idx];
        ldsT1[idx] = t1[b * 512 + idx];
    }
    __syncthreads();
    #pragma unroll 4
    for (int i = 0; i < 16; ++i) {
        int p = wv * 16 + i;
        float x = ldsA[p * 65 + lane];
        float ss = x * x;
        #pragma unroll
        for (int m = 1; m < 64; m <<= 1) ss += __shfl_xor(ss, m);
        if (lane == 0) sc[p] = 1.0f / fmaxf(sqrtf(ss), 1e-12f);
    }
    __syncthreads();
    int l = l0 + lane;
    bool valid = l < L_;
    int k0 = wv * 2, k1i = k0 + 1;
    float scv = sc[lane];
    float p0 = 1.0f, p1 = 1.0f;
    #pragma unroll 8
    for (int c = 0; c < 64; ++c) {
        float a = ldsA[lane * 65 + c] * scv;
        float z0 = (a - ldsMu[c * 8 + k0]) * ldsIs[c * 8 + k0];
        p0 *= ldsT1[c * 8 + k0] - 0.5f * z0 * z0;
        float z1 = (a - ldsMu[c * 8 + k1i]) * ldsIs[c * 8 + k1i];
        p1 *= ldsT1[c * 8 + k1i] - 0.5f * z1 * z1;
    }
    if (!valid) { p0 = 0.0f; p1 = 0.0f; }
    if (valid) {
        P[(size_t)(b * K_ + k0) * L_ + l] = p0;
        P[(size_t)(b * K_ + k1i) * L_ + l] = p1;
    }
    float v0 = p0 * p0, v1 = p1 * p1;
    #pragma unroll
    for (int m = 1; m < 64; m <<= 1) { v0 += __shfl_xor(v0, m); v1 += __shfl_xor(v1, m); }
    if (lane == 0) {
        Spart[(size_t)(b * K_ + k0) * LCH_ + lc] = v0;
        Spart[(size_t)(b * K_ + k1i) * LCH_ + lc] = v1;
    }
}

// kD: 16 blocks, one per b. In-block: gamma reduce + log-softmax, invn from
//     Spart, full-b LSE over 3900 l's -> part[b]. Only 16 agent-scope
//     release/acquire ops total (R7/R9 lesson: they cost ~an L2 flush each;
//     16 is negligible, 976 was fatal). Last block sums parts in fixed order.
__global__ __launch_bounds__(256) void kD(const float* __restrict__ P,
                                          const float* __restrict__ Spart,
                                          const float* __restrict__ gpartT,
                                          float* __restrict__ part,
                                          unsigned* __restrict__ ctr,
                                          float* __restrict__ out) {
    int b = blockIdx.x;
    int tid = threadIdx.x, lane = tid & 63, wv = tid >> 6;
    __shared__ float red8[8], lgk[8], invk[8];
    // gamma sums: wave wv handles k = 2wv, 2wv+1 (coalesced gpartT rows)
    {
        int k0 = wv * 2, k1i = k0 + 1;
        const float* s0 = gpartT + (size_t)(b * 8 + k0) * 975;
        const float* s1 = gpartT + (size_t)(b * 8 + k1i) * 975;
        float g0 = 0.f, g1 = 0.f;
        for (int i = lane; i < 975; i += 64) { g0 += s0[i]; g1 += s1[i]; }
        #pragma unroll
        for (int m = 1; m < 64; m <<= 1) { g0 += __shfl_xor(g0, m); g1 += __shfl_xor(g1, m); }
        if (lane == 0) { red8[k0] = g0; red8[k1i] = g1; }
    }
    __syncthreads();
    if (tid < 8) {
        float s = 0.0f;
        #pragma unroll 8
        for (int i = 0; i < LCH_; ++i) s += Spart[(size_t)(b * 8 + tid) * LCH_ + i];
        invk[tid] = 1.0f / fmaxf(sqrtf(s), 1e-12f);
    } else if (tid == 8) {
        float mx = -1e30f;
        #pragma unroll
        for (int k = 0; k < K_; ++k) mx = fmaxf(mx, red8[k]);
        float sum = 0.0f;
        #pragma unroll
        for (int k = 0; k < K_; ++k) sum += expf(red8[k] - mx);
        float lse = mx + logf(sum);
        #pragma unroll
        for (int k = 0; k < K_; ++k) lgk[k] = red8[k] - lse;
    }
    __syncthreads();
    float ik[K_], lg[K_];
    #pragma unroll
    for (int k = 0; k < K_; ++k) { ik[k] = invk[k]; lg[k] = lgk[k]; }
    float ll = 0.0f;
    for (int i = 0; i < 16; ++i) {
        int l = i * 256 + tid;
        if (l < L_) {
            float v[K_];
            float mx = -1e30f;
            #pragma unroll
            for (int k = 0; k < K_; ++k) {
                v[k] = P[(size_t)(b * K_ + k) * L_ + l] * ik[k] + lg[k];
                mx = fmaxf(mx, v[k]);
            }
            float s = 0.0f;
            #pragma unroll
            for (int k = 0; k < K_; ++k) s += expf(v[k] - mx);
            ll += mx + logf(s);
        }
    }
    #pragma unroll
    for (int m = 1; m < 64; m <<= 1) ll += __shfl_xor(ll, m);
    __shared__ float red[4];
    __shared__ bool last;
    if (lane == 0) red[wv] = ll;
    __syncthreads();
    if (tid == 0) {
        float v = red[0] + red[1] + red[2] + red[3];
        __hip_atomic_store(&part[b], v, __ATOMIC_RELEASE, __HIP_MEMORY_SCOPE_AGENT);
        unsigned old = __hip_atomic_fetch_add(ctr, 1u, __ATOMIC_ACQ_REL,
                                              __HIP_MEMORY_SCOPE_AGENT);
        last = (old == (unsigned)(B_ - 1));
    }
    __syncthreads();
    if (last && tid == 0) {
        double s = 0.0;
        #pragma unroll
        for (int b2 = 0; b2 < B_; ++b2)
            s += (double)__hip_atomic_load(&part[b2], __ATOMIC_ACQUIRE,
                                           __HIP_MEMORY_SCOPE_AGENT);
        out[0] = (float)(-s / ((double)B_ * (double)L_));
    }
}

extern "C" void kernel_launch(void* const* d_in, const int* in_sizes, int n_in,
                              void* d_out, int out_size, void* d_ws, size_t ws_size,
                              hipStream_t stream) {
    const float* rep     = (const float*)d_in[0];
    const float* rep_aug = (const float*)d_in[1];
    const float* Wg      = (const float*)d_in[2];
    const float* Wmu     = (const float*)d_in[3];
    const float* bmu     = (const float*)d_in[4];
    const float* Wsg     = (const float*)d_in[5];
    const float* bsg     = (const float*)d_in[6];
    float* out = (float*)d_out;
    float* ws  = (float*)d_ws;

    float* part    = ws + OFF_PART;
    unsigned* ctr  = (unsigned*)(ws + OFF_CTR);
    float* mus     = ws + OFF_MUS;
    float* isig    = ws + OFF_ISIG;
    float* t1      = ws + OFF_T1;
    float* Spart   = ws + OFF_SPART;
    float* gpartT  = ws + OFF_GPARTT;
    float* P       = ws + OFF_P;
    float* Aaug    = ws + OFF_AAUG;
    float* convp   = ws + OFF_CONVP;

    kA<<<B_ * LCH_, 256, 0, stream>>>(rep_aug, Wmu, Wsg, Aaug, convp);
    kB<<<975 + 64, 256, 0, stream>>>(Aaug, Wg, convp, bmu, bsg, gpartT, mus, isig, t1, ctr);
    kC<<<B_ * LCH_, 256, 0, stream>>>(rep, mus, isig, t1, P, Spart);
    kD<<<B_, 256, 0, stream>>>(P, Spart, gpartT, part, ctr, out);
}

// Round 11
// 63.565 us; speedup vs baseline: 1.4295x; 1.2547x over previous
//
#include <hip/hip_runtime.h>
#include <math.h>

#define B_ 16
#define T_ 12
#define N_ 325
#define C_ 64
#define K_ 8
#define L_ 3900            // N_*T_
#define M_ 249600          // C_*L_
#define LCH_ 61            // ceil(L_/64)
#define LOG2PI_ 1.8378770664093453f

// ---------------- workspace layout (floats) ----------------
#define OFF_LOGGAM 0            // 128
#define OFF_PART   128          // 256
#define OFF_CTR    384          // 1 unsigned
#define OFF_MUS    512          // 8192
#define OFF_ISIG   8704         // 8192
#define OFF_T1     16896        // 8192
#define OFF_SPART  25088        // 7808 = 128*61
#define OFF_GPART  32896        // 7808 = 976*8
#define OFF_P      40704        // 499200 = B*K*L
#define OFF_CONVP  539904       // 998400 = 61*16384
// total = 1538304 floats = 6.15 MB

// K1: block = (lc, b-pair). lc = bid&63 (same-lc blocks 64 apart -> same XCD,
//     each 128KB Wg slice lives in ONE L2). Stages 2 rep_aug tiles,
//     L2-normalizes in-LDS; each Wg load feeds 4 FMAs (2 b x 2 k).
//     (R9-proven body; R9's regression was k3's atomics, not this kernel.)
__global__ __launch_bounds__(256) void k1(const float* __restrict__ rep_aug,
                                          const float* __restrict__ Wg,
                                          const float* __restrict__ Wmu,
                                          const float* __restrict__ Wsg,
                                          float* __restrict__ gpart,
                                          float* __restrict__ convp) {
    int lc = blockIdx.x & 63, bp = blockIdx.x >> 6;
    if (lc >= LCH_) return;
    int b0 = bp * 2, b1 = b0 + 1;
    int l0 = lc * 64;
    __shared__ float ldsA0[64 * 65];     // [ll][c]
    __shared__ float ldsA1[64 * 65];
    __shared__ float sc0[64], sc1[64];
    __shared__ float ldsW[16 * 64];
    int tid = threadIdx.x, lane = tid & 63, wv = tid >> 6;
    const float4* r4 = (const float4*)rep_aug;
    for (int i4 = tid; i4 < 2048; i4 += 256) {
        int bsel = i4 >> 10, ll = (i4 >> 4) & 63, c4 = i4 & 15;
        int l = l0 + ll;
        int b = bsel ? b1 : b0;
        float4 v = make_float4(0.f, 0.f, 0.f, 0.f);
        if (l < L_) {
            int n = l / T_, t = l - n * T_;
            v = r4[(size_t)((b * T_ + t) * N_ + n) * 16 + c4];
        }
        float* dst = (bsel ? ldsA1 : ldsA0) + ll * 65 + c4 * 4;
        dst[0] = v.x; dst[1] = v.y; dst[2] = v.z; dst[3] = v.w;
    }
    for (int idx = tid; idx < 1024; idx += 256) {
        int r = idx >> 6, ll = idx & 63;
        int l = l0 + ll;
        float w = 0.0f;
        if (l < L_) w = (r < 8) ? Wmu[r * L_ + l] : Wsg[(r - 8) * L_ + l];
        ldsW[r * 64 + ll] = w;
    }
    __syncthreads();
    // sumsq: 128 rows (2 tiles x 64), 32 per wave
    #pragma unroll 4
    for (int i = 0; i < 32; ++i) {
        int p = wv * 32 + i;                 // 0..127
        float x = (p < 64 ? ldsA0[p * 65 + lane] : ldsA1[(p - 64) * 65 + lane]);
        float ss = x * x;
        #pragma unroll
        for (int m = 1; m < 64; m <<= 1) ss += __shfl_xor(ss, m);
        if (lane == 0) {
            float s = 1.0f / fmaxf(sqrtf(ss), 1e-12f);
            if (p < 64) sc0[p] = s; else sc1[p - 64] = s;
        }
    }
    __syncthreads();

    // ---- gamma partials: lane = l (coalesced Wg), wave wv owns k0,k1 ----
    int k0 = wv * 2, k1i = k0 + 1;
    int lg = l0 + lane;
    int lcl = lg < L_ ? lg : 0;              // invalid lanes have a==0
    const float* pg0 = Wg + (size_t)k0 * M_ + lcl;
    const float* pg1 = Wg + (size_t)k1i * M_ + lcl;
    float s0v = sc0[lane], s1v = sc1[lane];
    float g00 = 0.f, g01 = 0.f, g10 = 0.f, g11 = 0.f;
    #pragma unroll 8
    for (int c = 0; c < 64; ++c) {
        float w0 = pg0[(size_t)c * L_];
        float w1 = pg1[(size_t)c * L_];
        float a0 = ldsA0[lane * 65 + c] * s0v;
        float a1 = ldsA1[lane * 65 + c] * s1v;
        g00 = fmaf(a0, w0, g00);
        g01 = fmaf(a0, w1, g01);
        g10 = fmaf(a1, w0, g10);
        g11 = fmaf(a1, w1, g11);
    }
    #pragma unroll
    for (int m = 1; m < 64; m <<= 1) {
        g00 += __shfl_xor(g00, m); g01 += __shfl_xor(g01, m);
        g10 += __shfl_xor(g10, m); g11 += __shfl_xor(g11, m);
    }
    if (lane == 0) {
        gpart[(size_t)(lc * 16 + b0) * 8 + k0]  = g00;
        gpart[(size_t)(lc * 16 + b0) * 8 + k1i] = g01;
        gpart[(size_t)(lc * 16 + b1) * 8 + k0]  = g10;
        gpart[(size_t)(lc * 16 + b1) * 8 + k1i] = g11;
    }

    // ---- conv partials: c = lane, kk = wv (LDS-only), both b's ----
    int c = lane, kk = wv;
    const float* w0p = &ldsW[(kk * 4 + 0) * 64];
    const float* w1p = &ldsW[(kk * 4 + 1) * 64];
    const float* w2p = &ldsW[(kk * 4 + 2) * 64];
    const float* w3p = &ldsW[(kk * 4 + 3) * 64];
    float a00 = 0.f, a01 = 0.f, a02 = 0.f, a03 = 0.f;
    float a10 = 0.f, a11 = 0.f, a12 = 0.f, a13 = 0.f;
    #pragma unroll 8
    for (int l = 0; l < 64; ++l) {
        float av0 = ldsA0[l * 65 + c] * sc0[l];
        float av1 = ldsA1[l * 65 + c] * sc1[l];
        float w0 = w0p[l], w1 = w1p[l], w2 = w2p[l], w3 = w3p[l];
        a00 = fmaf(av0, w0, a00); a01 = fmaf(av0, w1, a01);
        a02 = fmaf(av0, w2, a02); a03 = fmaf(av0, w3, a03);
        a10 = fmaf(av1, w0, a10); a11 = fmaf(av1, w1, a11);
        a12 = fmaf(av1, w2, a12); a13 = fmaf(av1, w3, a13);
    }
    float* d0 = convp + (size_t)lc * 16384 + b0 * 1024 + c * 16 + kk * 4;
    d0[0] = a00; d0[1] = a01; d0[2] = a02; d0[3] = a03;
    float* d1 = convp + (size_t)lc * 16384 + b1 * 1024 + c * 16 + kk * 4;
    d1[0] = a10; d1[1] = a11; d1[2] = a12; d1[3] = a13;
}

// K2: convfin (blocks 0..63) + gamma reduce+log-softmax (64..79) + ctr reset
//     (R8-proven body)
__global__ __launch_bounds__(256) void k2(const float* __restrict__ convp,
                                          const float* __restrict__ gpart,
                                          const float* __restrict__ bmu,
                                          const float* __restrict__ bsg,
                                          float* __restrict__ mus,
                                          float* __restrict__ isig,
                                          float* __restrict__ t1,
                                          float* __restrict__ loggam,
                                          unsigned* __restrict__ ctr) {
    int tid = threadIdx.x;
    if (blockIdx.x < 64) {
        int o = blockIdx.x * 256 + tid;     // 0..16383 = b*1024 + c*16 + kk
        float s = 0.0f;
        #pragma unroll 8
        for (int lc = 0; lc < LCH_; ++lc) s += convp[(size_t)lc * 16384 + o];
        int bc = o >> 4, kk = o & 15, k = kk & 7;
        if (kk < 8) {
            mus[bc * 8 + k] = s + bmu[k];
        } else {
            float logit = s + bsg[k];
            isig[bc * 8 + k] = expf(-logit);
            t1[bc * 8 + k] = -logit - 0.5f * LOG2PI_;
        }
    } else {
        int b = blockIdx.x - 64;
        if (b == 0 && tid == 0) *ctr = 0u;   // reset k4's completion counter
        if (tid < 64) {
            int lc = tid;
            bool valid = lc < LCH_;
            float g[K_];
            #pragma unroll
            for (int k = 0; k < K_; ++k)
                g[k] = valid ? gpart[(size_t)(lc * 16 + b) * 8 + k] : 0.0f;
            #pragma unroll
            for (int k = 0; k < K_; ++k)
                #pragma unroll
                for (int m = 1; m < 64; m <<= 1) g[k] += __shfl_xor(g[k], m);
            if (tid == 0) {
                float mx = -1e30f;
                #pragma unroll
                for (int k = 0; k < K_; ++k) mx = fmaxf(mx, g[k]);
                float sum = 0.0f;
                #pragma unroll
                for (int k = 0; k < K_; ++k) sum += expf(g[k] - mx);
                float lse = mx + logf(sum);
                #pragma unroll
                for (int k = 0; k < K_; ++k) loggam[b * 8 + k] = g[k] - lse;
            }
        }
    }
}

// K3: prod only (R10-proven body). Block = (b, lc): P, Spart from raw rep.
__global__ __launch_bounds__(256) void k3(const float* __restrict__ rep,
                                          const float* __restrict__ mus,
                                          const float* __restrict__ isig,
                                          const float* __restrict__ t1,
                                          float* __restrict__ P,
                                          float* __restrict__ Spart) {
    int b = blockIdx.x & 15, lc = blockIdx.x >> 4;
    int l0 = lc * 64;
    __shared__ float ldsA[64 * 65];
    __shared__ float sc[64];
    __shared__ float ldsMu[512], ldsIs[512], ldsT1[512];
    int tid = threadIdx.x, lane = tid & 63, wv = tid >> 6;
    const float4* r4 = (const float4*)rep;
    for (int i4 = tid; i4 < 1024; i4 += 256) {
        int ll = i4 >> 4, c4 = i4 & 15;
        int l = l0 + ll;
        float4 v = make_float4(0.f, 0.f, 0.f, 0.f);
        if (l < L_) {
            int n = l / T_, t = l - n * T_;
            v = r4[(size_t)((b * T_ + t) * N_ + n) * 16 + c4];
        }
        int base = ll * 65 + c4 * 4;
        ldsA[base] = v.x; ldsA[base+1] = v.y; ldsA[base+2] = v.z; ldsA[base+3] = v.w;
    }
    for (int idx = tid; idx < 512; idx += 256) {
        ldsMu[idx] = mus[b * 512 + idx];
        ldsIs[idx] = isig[b * 512 + idx];
        ldsT1[idx] = t1[b * 512 + idx];
    }
    __syncthreads();
    #pragma unroll 4
    for (int i = 0; i < 16; ++i) {
        int p = wv * 16 + i;
        float x = ldsA[p * 65 + lane];
        float ss = x * x;
        #pragma unroll
        for (int m = 1; m < 64; m <<= 1) ss += __shfl_xor(ss, m);
        if (lane == 0) sc[p] = 1.0f / fmaxf(sqrtf(ss), 1e-12f);
    }
    __syncthreads();
    int l = l0 + lane;
    bool valid = l < L_;
    int k0 = wv * 2, k1i = k0 + 1;
    float scv = sc[lane];
    float p0 = 1.0f, p1 = 1.0f;
    #pragma unroll 8
    for (int c = 0; c < 64; ++c) {
        float a = ldsA[lane * 65 + c] * scv;
        float z0 = (a - ldsMu[c * 8 + k0]) * ldsIs[c * 8 + k0];
        p0 *= ldsT1[c * 8 + k0] - 0.5f * z0 * z0;
        float z1 = (a - ldsMu[c * 8 + k1i]) * ldsIs[c * 8 + k1i];
        p1 *= ldsT1[c * 8 + k1i] - 0.5f * z1 * z1;
    }
    if (!valid) { p0 = 0.0f; p1 = 0.0f; }
    if (valid) {
        P[(size_t)(b * K_ + k0) * L_ + l] = p0;
        P[(size_t)(b * K_ + k1i) * L_ + l] = p1;
    }
    float v0 = p0 * p0, v1 = p1 * p1;
    #pragma unroll
    for (int m = 1; m < 64; m <<= 1) { v0 += __shfl_xor(v0, m); v1 += __shfl_xor(v1, m); }
    if (lane == 0) {
        Spart[(size_t)(b * K_ + k0) * LCH_ + lc] = v0;
        Spart[(size_t)(b * K_ + k1i) * LCH_ + lc] = v1;
    }
}

// K4: per-(b,256-l): invn from Spart, LSE over k, block partial; last of 256
//     blocks reduces deterministically. 256 agent RMW total (R8-proven; the
//     ~1000-RMW and 16-block variants are both proven-bad — R9/R10).
__global__ __launch_bounds__(256) void k4(const float* __restrict__ P,
                                          const float* __restrict__ Spart,
                                          const float* __restrict__ loggam,
                                          float* __restrict__ part,
                                          unsigned* __restrict__ ctr,
                                          float* __restrict__ out) {
    int b = blockIdx.x >> 4, ch = blockIdx.x & 15;
    int tid = threadIdx.x, lane = tid & 63, wv = tid >> 6;
    __shared__ float invk[8], lgk[8];
    if (tid < 8) {
        float s = 0.0f;
        #pragma unroll 8
        for (int i = 0; i < LCH_; ++i) s += Spart[(size_t)(b * 8 + tid) * LCH_ + i];
        invk[tid] = 1.0f / fmaxf(sqrtf(s), 1e-12f);
        lgk[tid] = loggam[b * 8 + tid];
    }
    __syncthreads();
    int l = ch * 256 + tid;
    float ll = 0.0f;
    if (l < L_) {
        float v[K_];
        float mx = -1e30f;
        #pragma unroll
        for (int k = 0; k < K_; ++k) {
            v[k] = P[(size_t)(b * K_ + k) * L_ + l] * invk[k] + lgk[k];
            mx = fmaxf(mx, v[k]);
        }
        float s = 0.0f;
        #pragma unroll
        for (int k = 0; k < K_; ++k) s += expf(v[k] - mx);
        ll = mx + logf(s);
    }
    #pragma unroll
    for (int m = 1; m < 64; m <<= 1) ll += __shfl_xor(ll, m);
    __shared__ float red[4];
    __shared__ bool last;
    if (lane == 0) red[wv] = ll;
    __syncthreads();
    if (tid == 0) {
        float v = red[0] + red[1] + red[2] + red[3];
        __hip_atomic_store(&part[blockIdx.x], v, __ATOMIC_RELEASE, __HIP_MEMORY_SCOPE_AGENT);
        unsigned old = __hip_atomic_fetch_add(ctr, 1u, __ATOMIC_ACQ_REL, __HIP_MEMORY_SCOPE_AGENT);
        last = (old == 255u);
    }
    __syncthreads();
    if (last) {
        float v = __hip_atomic_load(&part[tid], __ATOMIC_ACQUIRE, __HIP_MEMORY_SCOPE_AGENT);
        double d = (double)v;
        #pragma unroll
        for (int m = 1; m < 64; m <<= 1) d += __shfl_xor(d, m);
        __shared__ double dred[4];
        if (lane == 0) dred[wv] = d;
        __syncthreads();
        if (tid == 0)
            out[0] = (float)(-(dred[0] + dred[1] + dred[2] + dred[3]) /
                             ((double)B_ * (double)L_));
    }
}

extern "C" void kernel_launch(void* const* d_in, const int* in_sizes, int n_in,
                              void* d_out, int out_size, void* d_ws, size_t ws_size,
                              hipStream_t stream) {
    const float* rep     = (const float*)d_in[0];
    const float* rep_aug = (const float*)d_in[1];
    const float* Wg      = (const float*)d_in[2];
    const float* Wmu     = (const float*)d_in[3];
    const float* bmu     = (const float*)d_in[4];
    const float* Wsg     = (const float*)d_in[5];
    const float* bsg     = (const float*)d_in[6];
    float* out = (float*)d_out;
    float* ws  = (float*)d_ws;

    float* loggam  = ws + OFF_LOGGAM;
    float* part    = ws + OFF_PART;
    unsigned* ctr  = (unsigned*)(ws + OFF_CTR);
    float* mus     = ws + OFF_MUS;
    float* isig    = ws + OFF_ISIG;
    float* t1      = ws + OFF_T1;
    float* Spart   = ws + OFF_SPART;
    float* gpart   = ws + OFF_GPART;
    float* P       = ws + OFF_P;
    float* convp   = ws + OFF_CONVP;

    k1<<<512, 256, 0, stream>>>(rep_aug, Wg, Wmu, Wsg, gpart, convp);
    k2<<<80, 256, 0, stream>>>(convp, gpart, bmu, bsg, mus, isig, t1, loggam, ctr);
    k3<<<B_ * LCH_, 256, 0, stream>>>(rep, mus, isig, t1, P, Spart);
    k4<<<B_ * 16, 256, 0, stream>>>(P, Spart, loggam, part, ctr, out);
}